// Round 7
// baseline (931.005 us; speedup 1.0000x reference)
//
#include <hip/hip_runtime.h>
#include <math.h>

#define IN_CH 256
#define OUT_CH 64
#define BK_LOG 8
#define BK_NODES 256            // nodes per bucket
#define NBK_CAP 1024            // max buckets supported (N <= 262144)
#define DIST_TILE 16384         // edges per distribute block

// ---------------------------------------------------------------------------
__global__ void k_zero(int* __restrict__ p, int n) {
    int i = blockIdx.x * blockDim.x + threadIdx.x;
    if (i < n) p[i] = 0;
}

// ---------------------------------------------------------------------------
// Per-block LDS histogram of bucket ids; flush with one atomic per bucket.
// ---------------------------------------------------------------------------
__global__ void k_bcount(const int* __restrict__ dst, int* __restrict__ bucketCnt,
                         int E, int nbk) {
    __shared__ int hist[NBK_CAP];
    const int tid = threadIdx.x;
    for (int b = tid; b < nbk; b += blockDim.x) hist[b] = 0;
    __syncthreads();
    int i = blockIdx.x * blockDim.x + tid;
    const int stride = gridDim.x * blockDim.x;
    for (; i < E; i += stride) atomicAdd(&hist[dst[i] >> BK_LOG], 1);
    __syncthreads();
    for (int b = tid; b < nbk; b += blockDim.x)
        if (hist[b]) atomicAdd(&bucketCnt[b], hist[b]);
}

// ---------------------------------------------------------------------------
// Exclusive scan of bucketCnt -> bucketOffs[0..nbk], bucketCur = offs.
// ---------------------------------------------------------------------------
__global__ void k_bscan(const int* __restrict__ bucketCnt, int* __restrict__ bucketOffs,
                        int* __restrict__ bucketCur, int nbk) {
    __shared__ int sdata[NBK_CAP];
    const int t = threadIdx.x;
    const int orig = (t < nbk) ? bucketCnt[t] : 0;
    sdata[t] = orig;
    __syncthreads();
    for (int off = 1; off < NBK_CAP; off <<= 1) {
        int v = (t >= off) ? sdata[t - off] : 0;
        __syncthreads();
        sdata[t] += v;
        __syncthreads();
    }
    if (t < nbk) {
        const int excl = sdata[t] - orig;
        bucketOffs[t] = excl;
        bucketCur[t] = excl;
        if (t == nbk - 1) bucketOffs[nbk] = sdata[t];
    }
}

// ---------------------------------------------------------------------------
// Bucket-sort edges: per-block LDS count, one global reservation per bucket
// per block, then scatter into contiguous per-block runs (~168 B / bucket).
// ---------------------------------------------------------------------------
__global__ __launch_bounds__(256) void k_distribute(
    const int* __restrict__ src, const int* __restrict__ dst,
    int* __restrict__ bucketCur, int* __restrict__ srcS, int* __restrict__ dstS,
    int E, int nbk)
{
    __shared__ int hist[NBK_CAP];
    __shared__ int base[NBK_CAP];
    const int tid = threadIdx.x;
    const int t0 = blockIdx.x * DIST_TILE;
    const int t1 = min(E, t0 + DIST_TILE);

    for (int b = tid; b < nbk; b += 256) hist[b] = 0;
    __syncthreads();
    for (int i = t0 + tid; i < t1; i += 256) atomicAdd(&hist[dst[i] >> BK_LOG], 1);
    __syncthreads();
    for (int b = tid; b < nbk; b += 256)
        base[b] = hist[b] ? atomicAdd(&bucketCur[b], hist[b]) : 0;
    __syncthreads();
    for (int i = t0 + tid; i < t1; i += 256) {
        const int d = dst[i];
        const int p = atomicAdd(&base[d >> BK_LOG], 1);
        srcS[p] = src[i];
        dstS[p] = d;
    }
}

// ---------------------------------------------------------------------------
// Per-bucket local degree histogram -> dinv[node] = rsqrt(deg+1).
// ---------------------------------------------------------------------------
__global__ __launch_bounds__(256) void k_deg(const int* __restrict__ dstS,
                                             const int* __restrict__ bucketOffs,
                                             float* __restrict__ dinv, int N) {
    __shared__ int hist[BK_NODES];
    const int tid = threadIdx.x;
    const int b = blockIdx.x;
    hist[tid] = 0;
    __syncthreads();
    const int bo = bucketOffs[b], eo = bucketOffs[b + 1];
    for (int i = bo + tid; i < eo; i += 256) atomicAdd(&hist[dstS[i] & (BK_NODES - 1)], 1);
    __syncthreads();
    const int node = b * BK_NODES + tid;
    if (node < N) dinv[node] = rsqrtf((float)hist[tid] + 1.0f);
}

// ---------------------------------------------------------------------------
// h = x @ W (unscaled). 512 thr: 64 slots x 8 cg; 4 rows/slot (W-read reuse).
// ---------------------------------------------------------------------------
__global__ __launch_bounds__(512) void k_gemm(
    const float* __restrict__ x, const float* __restrict__ W,
    float* __restrict__ h, int N)
{
    __shared__ float Wlds[IN_CH * OUT_CH];  // 64 KB
    const int tid = threadIdx.x;
    for (int i = tid * 4; i < IN_CH * OUT_CH; i += 512 * 4) {
        *(float4*)&Wlds[i] = *(const float4*)&W[i];
    }
    __syncthreads();

    const int slot = tid >> 3;
    const int cg = (tid & 7) * 8;
    const int row0 = blockIdx.x * 256 + slot * 4;

    float a[4][8];
#pragma unroll
    for (int r = 0; r < 4; ++r)
#pragma unroll
        for (int c = 0; c < 8; ++c) a[r][c] = 0.f;

    const int rmax = (row0 + 4 <= N) ? 4 : max(0, N - row0);

    for (int k = 0; k < IN_CH; k += 4) {
        float4 xv[4];
#pragma unroll
        for (int r = 0; r < 4; ++r) {
            const int row = (r < rmax) ? (row0 + r) : (N - 1);
            xv[r] = *(const float4*)&x[(size_t)row * IN_CH + k];
        }
        const float xs[4][4] = {
            {xv[0].x, xv[0].y, xv[0].z, xv[0].w},
            {xv[1].x, xv[1].y, xv[1].z, xv[1].w},
            {xv[2].x, xv[2].y, xv[2].z, xv[2].w},
            {xv[3].x, xv[3].y, xv[3].z, xv[3].w}};
#pragma unroll
        for (int kk = 0; kk < 4; ++kk) {
            const float4 w0 = *(const float4*)&Wlds[(k + kk) * OUT_CH + cg];
            const float4 w1 = *(const float4*)&Wlds[(k + kk) * OUT_CH + cg + 4];
#pragma unroll
            for (int r = 0; r < 4; ++r) {
                a[r][0] += xs[r][kk] * w0.x; a[r][1] += xs[r][kk] * w0.y;
                a[r][2] += xs[r][kk] * w0.z; a[r][3] += xs[r][kk] * w0.w;
                a[r][4] += xs[r][kk] * w1.x; a[r][5] += xs[r][kk] * w1.y;
                a[r][6] += xs[r][kk] * w1.z; a[r][7] += xs[r][kk] * w1.w;
            }
        }
    }

#pragma unroll
    for (int r = 0; r < 4; ++r) {
        if (r < rmax) {
            const size_t o = (size_t)(row0 + r) * OUT_CH + cg;
            *(float4*)&h[o]     = make_float4(a[r][0], a[r][1], a[r][2], a[r][3]);
            *(float4*)&h[o + 4] = make_float4(a[r][4], a[r][5], a[r][6], a[r][7]);
        }
    }
}

// ---------------------------------------------------------------------------
// One block per bucket. LDS fp32 accumulator acc[256][64]; waves stream the
// bucket's contiguous edges, gather h[src] (256 B coalesced), ds_add into LDS.
// Epilogue: z = dinv_i*(acc + dinv_i*h_i) + b, fused log_softmax.
// ---------------------------------------------------------------------------
__global__ __launch_bounds__(256) void k_aggregate(
    const int* __restrict__ srcS, const int* __restrict__ dstS,
    const int* __restrict__ bucketOffs, const float* __restrict__ h,
    const float* __restrict__ dinv, const float* __restrict__ bvec,
    float* __restrict__ out, int N)
{
    __shared__ float acc[BK_NODES * OUT_CH];  // 64 KB
    const int tid = threadIdx.x;
    const int lane = tid & 63;
    const int wv = tid >> 6;  // 0..3

    for (int i = tid * 4; i < BK_NODES * OUT_CH; i += 256 * 4)
        *(float4*)&acc[i] = make_float4(0.f, 0.f, 0.f, 0.f);
    __syncthreads();

    const int b = blockIdx.x;
    const int bo = bucketOffs[b], eo = bucketOffs[b + 1];

    for (int e0 = bo + wv * 64; e0 < eo; e0 += 4 * 64) {
        const int n = min(64, eo - e0);
        const int idx = (lane < n) ? srcS[e0 + lane] : 0;
        const int dl  = (lane < n) ? (dstS[e0 + lane] & (BK_NODES - 1)) : 0;
        const float dv = (lane < n) ? dinv[idx] : 0.f;
        for (int j = 0; j < n; ++j) {
            const int s   = __shfl(idx, j);
            const int dll = __shfl(dl, j);
            const float w = __shfl(dv, j);
            const float v = h[(size_t)s * OUT_CH + lane] * w;
            atomicAdd(&acc[dll * OUT_CH + lane], v);
        }
    }
    __syncthreads();

    const float bc = bvec[lane];
    for (int nl = wv * 64; nl < wv * 64 + 64; ++nl) {
        const int node = b * BK_NODES + nl;
        if (node >= N) break;
        const float di = dinv[node];
        const float selfv = h[(size_t)node * OUT_CH + lane];
        const float z = di * (acc[nl * OUT_CH + lane] + di * selfv) + bc;

        float m = z;
#pragma unroll
        for (int off = 32; off; off >>= 1) m = fmaxf(m, __shfl_xor(m, off));
        float ev = __expf(z - m);
        float s = ev;
#pragma unroll
        for (int off = 32; off; off >>= 1) s += __shfl_xor(s, off);
        out[(size_t)node * OUT_CH + lane] = z - m - __logf(s);
    }
}

// ---------------------------------------------------------------------------
extern "C" void kernel_launch(void* const* d_in, const int* in_sizes, int n_in,
                              void* d_out, int out_size, void* d_ws, size_t ws_size,
                              hipStream_t stream) {
    const float* x  = (const float*)d_in[0];
    const int*   ei = (const int*)d_in[1];
    const float* W  = (const float*)d_in[2];
    const float* b  = (const float*)d_in[3];
    float* out = (float*)d_out;

    const int N = in_sizes[0] / IN_CH;  // 100000
    const int E = in_sizes[1] / 2;      // 1600000
    const int* src = ei;
    const int* dst = ei + E;

    const int nbk = (N + BK_NODES - 1) >> BK_LOG;          // 391
    const int ndist = (E + DIST_TILE - 1) / DIST_TILE;     // 98

    // ws: bucketCnt[1024] | bucketOffs[1025] | bucketCur[1024] |
    //     srcS[E] | dstS[E] | dinv[N] | h[N*64]            (~39 MB)
    char* p = (char*)d_ws;
    auto alloc = [&](size_t bytes) { char* q = p; p += (bytes + 255) & ~(size_t)255; return q; };
    int*   bucketCnt  = (int*)alloc(NBK_CAP * 4);
    int*   bucketOffs = (int*)alloc((NBK_CAP + 1) * 4);
    int*   bucketCur  = (int*)alloc(NBK_CAP * 4);
    int*   srcS       = (int*)alloc((size_t)E * 4);
    int*   dstS       = (int*)alloc((size_t)E * 4);
    float* dinv       = (float*)alloc((size_t)N * 4);
    float* h          = (float*)alloc((size_t)N * OUT_CH * 4);

    k_zero      <<<(nbk + 255) / 256, 256, 0, stream>>>(bucketCnt, nbk);
    k_bcount    <<<392, 256, 0, stream>>>(dst, bucketCnt, E, nbk);
    k_bscan     <<<1, NBK_CAP, 0, stream>>>(bucketCnt, bucketOffs, bucketCur, nbk);
    k_distribute<<<ndist, 256, 0, stream>>>(src, dst, bucketCur, srcS, dstS, E, nbk);
    k_deg       <<<nbk, 256, 0, stream>>>(dstS, bucketOffs, dinv, N);
    k_gemm      <<<(N + 255) / 256, 512, 0, stream>>>(x, W, h, N);
    k_aggregate <<<nbk, 256, 0, stream>>>(srcS, dstS, bucketOffs, h, dinv, b, out, N);
}

// Round 8
// 255.759 us; speedup vs baseline: 3.6402x; 3.6402x over previous
//
#include <hip/hip_runtime.h>
#include <math.h>

#define IN_CH 256
#define OUT_CH 64
#define BK_LOG 8
#define BK_NODES 256            // nodes per bucket
#define NBK_CAP 1024            // max buckets (N <= 262144)
#define DIST_TILE 16384         // edges per distribute block

// ---------------------------------------------------------------------------
__global__ void k_zero(int* __restrict__ p, int n) {
    int i = blockIdx.x * blockDim.x + threadIdx.x;
    if (i < n) p[i] = 0;
}

// ---------------------------------------------------------------------------
// Per-block LDS histogram of bucket ids; flush with one atomic per bucket.
// ---------------------------------------------------------------------------
__global__ void k_bcount(const int* __restrict__ dst, int* __restrict__ bucketCnt,
                         int E, int nbk) {
    __shared__ int hist[NBK_CAP];
    const int tid = threadIdx.x;
    for (int b = tid; b < nbk; b += blockDim.x) hist[b] = 0;
    __syncthreads();
    int i = blockIdx.x * blockDim.x + tid;
    const int stride = gridDim.x * blockDim.x;
    for (; i < E; i += stride) atomicAdd(&hist[dst[i] >> BK_LOG], 1);
    __syncthreads();
    for (int b = tid; b < nbk; b += blockDim.x)
        if (hist[b]) atomicAdd(&bucketCnt[b], hist[b]);
}

// ---------------------------------------------------------------------------
// Exclusive scan of bucketCnt -> bucketOffs[0..nbk]; bucketCur = offs.
// ---------------------------------------------------------------------------
__global__ void k_bscan(const int* __restrict__ bucketCnt, int* __restrict__ bucketOffs,
                        int* __restrict__ bucketCur, int nbk) {
    __shared__ int sdata[NBK_CAP];
    const int t = threadIdx.x;
    const int orig = (t < nbk) ? bucketCnt[t] : 0;
    sdata[t] = orig;
    __syncthreads();
    for (int off = 1; off < NBK_CAP; off <<= 1) {
        int v = (t >= off) ? sdata[t - off] : 0;
        __syncthreads();
        sdata[t] += v;
        __syncthreads();
    }
    if (t < nbk) {
        const int excl = sdata[t] - orig;
        bucketOffs[t] = excl;
        bucketCur[t] = excl;
        if (t == nbk - 1) bucketOffs[nbk] = sdata[t];
    }
}

// ---------------------------------------------------------------------------
// Bucket-sort edges into packed[] = src | (dst&255)<<24, contiguous per-block
// runs reserved with one global atomic per bucket per block.
// ---------------------------------------------------------------------------
__global__ __launch_bounds__(256) void k_distribute(
    const int* __restrict__ src, const int* __restrict__ dst,
    int* __restrict__ bucketCur, unsigned int* __restrict__ packed,
    int E, int nbk)
{
    __shared__ int hist[NBK_CAP];
    __shared__ int base[NBK_CAP];
    const int tid = threadIdx.x;
    const int t0 = blockIdx.x * DIST_TILE;
    const int t1 = min(E, t0 + DIST_TILE);

    for (int b = tid; b < nbk; b += 256) hist[b] = 0;
    __syncthreads();
    for (int i = t0 + tid; i < t1; i += 256) atomicAdd(&hist[dst[i] >> BK_LOG], 1);
    __syncthreads();
    for (int b = tid; b < nbk; b += 256)
        base[b] = hist[b] ? atomicAdd(&bucketCur[b], hist[b]) : 0;
    __syncthreads();
    for (int i = t0 + tid; i < t1; i += 256) {
        const int d = dst[i];
        const int p = atomicAdd(&base[d >> BK_LOG], 1);
        packed[p] = (unsigned int)src[i] | ((unsigned int)(d & (BK_NODES - 1)) << 24);
    }
}

// ---------------------------------------------------------------------------
// One block per bucket: LDS histogram of local dst -> per-node offs + dinv,
// then LDS-cursor counting sort to exact dst order: list[p] = src.
// Scattered writes span only ~16 KB -> L2 coalesces them.
// ---------------------------------------------------------------------------
__global__ __launch_bounds__(256) void k_sortbucket(
    const unsigned int* __restrict__ packed, const int* __restrict__ bucketOffs,
    int* __restrict__ offs, int* __restrict__ list, float* __restrict__ dinv, int N)
{
    __shared__ int hist[BK_NODES];
    __shared__ int scan[BK_NODES];
    const int tid = threadIdx.x;
    const int b = blockIdx.x;
    const int bo = bucketOffs[b], eo = bucketOffs[b + 1];

    hist[tid] = 0;
    __syncthreads();
    for (int i = bo + tid; i < eo; i += 256)
        atomicAdd(&hist[packed[i] >> 24], 1);
    __syncthreads();

    // Hillis-Steele inclusive scan of hist -> scan
    int v = hist[tid];
    scan[tid] = v;
    __syncthreads();
    for (int off = 1; off < BK_NODES; off <<= 1) {
        int u = (tid >= off) ? scan[tid - off] : 0;
        __syncthreads();
        scan[tid] += u;
        __syncthreads();
    }
    const int excl = scan[tid] - v;

    const int node = b * BK_NODES + tid;
    if (node < N) {
        offs[node] = bo + excl;
        dinv[node] = rsqrtf((float)v + 1.0f);   // +1 self loop
        if (node == N - 1) offs[N] = eo;
    }

    // reuse hist as cursor
    hist[tid] = bo + excl;
    __syncthreads();
    for (int i = bo + tid; i < eo; i += 256) {
        const unsigned int pv = packed[i];
        const int p = atomicAdd(&hist[pv >> 24], 1);
        list[p] = (int)(pv & 0xFFFFFFu);
    }
}

// ---------------------------------------------------------------------------
// g = (x @ W) * dinv[row].  512 thr: 64 slots x 8 cg; 4 rows/slot.
// ---------------------------------------------------------------------------
__global__ __launch_bounds__(512) void k_gemm_scale(
    const float* __restrict__ x, const float* __restrict__ W,
    const float* __restrict__ dinv, float* __restrict__ g, int N)
{
    __shared__ float Wlds[IN_CH * OUT_CH];  // 64 KB
    const int tid = threadIdx.x;
    for (int i = tid * 4; i < IN_CH * OUT_CH; i += 512 * 4) {
        *(float4*)&Wlds[i] = *(const float4*)&W[i];
    }
    __syncthreads();

    const int slot = tid >> 3;
    const int cg = (tid & 7) * 8;
    const int row0 = blockIdx.x * 256 + slot * 4;

    float a[4][8];
#pragma unroll
    for (int r = 0; r < 4; ++r)
#pragma unroll
        for (int c = 0; c < 8; ++c) a[r][c] = 0.f;

    const int rmax = (row0 + 4 <= N) ? 4 : max(0, N - row0);

    for (int k = 0; k < IN_CH; k += 4) {
        float4 xv[4];
#pragma unroll
        for (int r = 0; r < 4; ++r) {
            const int row = (r < rmax) ? (row0 + r) : (N - 1);
            xv[r] = *(const float4*)&x[(size_t)row * IN_CH + k];
        }
        const float xs[4][4] = {
            {xv[0].x, xv[0].y, xv[0].z, xv[0].w},
            {xv[1].x, xv[1].y, xv[1].z, xv[1].w},
            {xv[2].x, xv[2].y, xv[2].z, xv[2].w},
            {xv[3].x, xv[3].y, xv[3].z, xv[3].w}};
#pragma unroll
        for (int kk = 0; kk < 4; ++kk) {
            const float4 w0 = *(const float4*)&Wlds[(k + kk) * OUT_CH + cg];
            const float4 w1 = *(const float4*)&Wlds[(k + kk) * OUT_CH + cg + 4];
#pragma unroll
            for (int r = 0; r < 4; ++r) {
                a[r][0] += xs[r][kk] * w0.x; a[r][1] += xs[r][kk] * w0.y;
                a[r][2] += xs[r][kk] * w0.z; a[r][3] += xs[r][kk] * w0.w;
                a[r][4] += xs[r][kk] * w1.x; a[r][5] += xs[r][kk] * w1.y;
                a[r][6] += xs[r][kk] * w1.z; a[r][7] += xs[r][kk] * w1.w;
            }
        }
    }

#pragma unroll
    for (int r = 0; r < 4; ++r) {
        if (r < rmax) {
            const int row = row0 + r;
            const float dv = dinv[row];
            const size_t o = (size_t)row * OUT_CH + cg;
            *(float4*)&g[o]     = make_float4(a[r][0]*dv, a[r][1]*dv, a[r][2]*dv, a[r][3]*dv);
            *(float4*)&g[o + 4] = make_float4(a[r][4]*dv, a[r][5]*dv, a[r][6]*dv, a[r][7]*dv);
        }
    }
}

// ---------------------------------------------------------------------------
// One wave per node: parallel gathers over CSR list + fused bias/log_softmax.
// 16K waves restore the TLP that hides gather latency.
// ---------------------------------------------------------------------------
__global__ void k_aggregate(const int* __restrict__ offs, const int* __restrict__ list,
                            const float* __restrict__ g, const float* __restrict__ b,
                            float* __restrict__ out, int N)
{
    const int lane = threadIdx.x & 63;
    int wid = (blockIdx.x * blockDim.x + threadIdx.x) >> 6;
    const int nw = (gridDim.x * blockDim.x) >> 6;
    const float bc = b[lane];

    for (int i = wid; i < N; i += nw) {
        const int start = offs[i];
        const int end = offs[i + 1];
        float acc = g[(size_t)i * OUT_CH + lane];  // self loop

        for (int e0 = start; e0 < end; e0 += 64) {
            const int n = min(64, end - e0);
            const int idx = (lane < n) ? list[e0 + lane] : 0;
            for (int j = 0; j < n; ++j) {
                const int s = __shfl(idx, j);
                acc += g[(size_t)s * OUT_CH + lane];
            }
        }

        const float dinv = rsqrtf((float)(end - start + 1));
        const float z = acc * dinv + bc;

        float m = z;
#pragma unroll
        for (int off = 32; off; off >>= 1) m = fmaxf(m, __shfl_xor(m, off));
        float ev = __expf(z - m);
        float s = ev;
#pragma unroll
        for (int off = 32; off; off >>= 1) s += __shfl_xor(s, off);
        out[(size_t)i * OUT_CH + lane] = z - m - __logf(s);
    }
}

// ---------------------------------------------------------------------------
extern "C" void kernel_launch(void* const* d_in, const int* in_sizes, int n_in,
                              void* d_out, int out_size, void* d_ws, size_t ws_size,
                              hipStream_t stream) {
    const float* x  = (const float*)d_in[0];
    const int*   ei = (const int*)d_in[1];
    const float* W  = (const float*)d_in[2];
    const float* b  = (const float*)d_in[3];
    float* out = (float*)d_out;

    const int N = in_sizes[0] / IN_CH;  // 100000
    const int E = in_sizes[1] / 2;      // 1600000
    const int* src = ei;
    const int* dst = ei + E;

    const int nbk = (N + BK_NODES - 1) >> BK_LOG;          // 391
    const int ndist = (E + DIST_TILE - 1) / DIST_TILE;     // 98

    // ws: bucketCnt[1024] | bucketOffs[1025] | bucketCur[1024] |
    //     packed[E] | list[E] | offs[N+1] | dinv[N] | g[N*64]   (~39 MB)
    char* p = (char*)d_ws;
    auto alloc = [&](size_t bytes) { char* q = p; p += (bytes + 255) & ~(size_t)255; return q; };
    int*          bucketCnt  = (int*)alloc(NBK_CAP * 4);
    int*          bucketOffs = (int*)alloc((NBK_CAP + 1) * 4);
    int*          bucketCur  = (int*)alloc(NBK_CAP * 4);
    unsigned int* packed     = (unsigned int*)alloc((size_t)E * 4);
    int*          list       = (int*)alloc((size_t)E * 4);
    int*          offs       = (int*)alloc((size_t)(N + 1) * 4);
    float*        dinv       = (float*)alloc((size_t)N * 4);
    float*        g          = (float*)alloc((size_t)N * OUT_CH * 4);

    k_zero      <<<(nbk + 255) / 256, 256, 0, stream>>>(bucketCnt, nbk);
    k_bcount    <<<392, 256, 0, stream>>>(dst, bucketCnt, E, nbk);
    k_bscan     <<<1, NBK_CAP, 0, stream>>>(bucketCnt, bucketOffs, bucketCur, nbk);
    k_distribute<<<ndist, 256, 0, stream>>>(src, dst, bucketCur, packed, E, nbk);
    k_sortbucket<<<nbk, 256, 0, stream>>>(packed, bucketOffs, offs, list, dinv, N);
    k_gemm_scale<<<(N + 255) / 256, 512, 0, stream>>>(x, W, dinv, g, N);
    k_aggregate <<<4096, 256, 0, stream>>>(offs, list, g, b, out, N);
}

// Round 10
// 254.453 us; speedup vs baseline: 3.6589x; 1.0051x over previous
//
#include <hip/hip_runtime.h>
#include <math.h>

#define IN_CH 256
#define OUT_CH 64
#define BK_LOG 8
#define BK_NODES 256            // nodes per bucket
#define NBK_CAP 1024            // max buckets (N <= 262144)
#define DIST_TILE 16384         // edges per distribute block

typedef unsigned short ushort_t;
typedef unsigned int uint_t;

__device__ __forceinline__ float b2f(ushort_t u) {
    union { uint_t i; float f; } c; c.i = ((uint_t)u) << 16; return c.f;
}
__device__ __forceinline__ uint_t f2b(float f) {  // round-to-nearest-even
    union { float f; uint_t i; } c; c.f = f;
    return (c.i + 0x7FFFu + ((c.i >> 16) & 1u)) >> 16;
}

// ---------------------------------------------------------------------------
__global__ void k_zero(int* __restrict__ p, int n) {
    int i = blockIdx.x * blockDim.x + threadIdx.x;
    if (i < n) p[i] = 0;
}

// ---------------------------------------------------------------------------
// Per-block LDS histogram of bucket ids; flush with one atomic per bucket.
// ---------------------------------------------------------------------------
__global__ void k_bcount(const int* __restrict__ dst, int* __restrict__ bucketCnt,
                         int E, int nbk) {
    __shared__ int hist[NBK_CAP];
    const int tid = threadIdx.x;
    for (int b = tid; b < nbk; b += blockDim.x) hist[b] = 0;
    __syncthreads();
    int i = blockIdx.x * blockDim.x + tid;
    const int stride = gridDim.x * blockDim.x;
    for (; i < E; i += stride) atomicAdd(&hist[dst[i] >> BK_LOG], 1);
    __syncthreads();
    for (int b = tid; b < nbk; b += blockDim.x)
        if (hist[b]) atomicAdd(&bucketCnt[b], hist[b]);
}

// ---------------------------------------------------------------------------
// Exclusive scan of bucketCnt -> bucketOffs[0..nbk]; bucketCur = offs.
// ---------------------------------------------------------------------------
__global__ void k_bscan(const int* __restrict__ bucketCnt, int* __restrict__ bucketOffs,
                        int* __restrict__ bucketCur, int nbk) {
    __shared__ int sdata[NBK_CAP];
    const int t = threadIdx.x;
    const int orig = (t < nbk) ? bucketCnt[t] : 0;
    sdata[t] = orig;
    __syncthreads();
    for (int off = 1; off < NBK_CAP; off <<= 1) {
        int v = (t >= off) ? sdata[t - off] : 0;
        __syncthreads();
        sdata[t] += v;
        __syncthreads();
    }
    if (t < nbk) {
        const int excl = sdata[t] - orig;
        bucketOffs[t] = excl;
        bucketCur[t] = excl;
        if (t == nbk - 1) bucketOffs[nbk] = sdata[t];
    }
}

// ---------------------------------------------------------------------------
// Bucket-sort edges into packed[] = src | (dst&255)<<24, contiguous per-block
// runs reserved with one global atomic per bucket per block.
// ---------------------------------------------------------------------------
__global__ __launch_bounds__(256) void k_distribute(
    const int* __restrict__ src, const int* __restrict__ dst,
    int* __restrict__ bucketCur, uint_t* __restrict__ packed,
    int E, int nbk)
{
    __shared__ int hist[NBK_CAP];
    __shared__ int base[NBK_CAP];
    const int tid = threadIdx.x;
    const int t0 = blockIdx.x * DIST_TILE;
    const int t1 = min(E, t0 + DIST_TILE);

    for (int b = tid; b < nbk; b += 256) hist[b] = 0;
    __syncthreads();
    for (int i = t0 + tid; i < t1; i += 256) atomicAdd(&hist[dst[i] >> BK_LOG], 1);
    __syncthreads();
    for (int b = tid; b < nbk; b += 256)
        base[b] = hist[b] ? atomicAdd(&bucketCur[b], hist[b]) : 0;
    __syncthreads();
    for (int i = t0 + tid; i < t1; i += 256) {
        const int d = dst[i];
        const int p = atomicAdd(&base[d >> BK_LOG], 1);
        packed[p] = (uint_t)src[i] | ((uint_t)(d & (BK_NODES - 1)) << 24);
    }
}

// ---------------------------------------------------------------------------
// One block per bucket: LDS histogram of local dst -> per-node offs + dinv,
// then LDS-cursor counting sort to exact dst order: list[p] = src.
// ---------------------------------------------------------------------------
__global__ __launch_bounds__(256) void k_sortbucket(
    const uint_t* __restrict__ packed, const int* __restrict__ bucketOffs,
    int* __restrict__ offs, int* __restrict__ list, float* __restrict__ dinv, int N)
{
    __shared__ int hist[BK_NODES];
    __shared__ int scan[BK_NODES];
    const int tid = threadIdx.x;
    const int b = blockIdx.x;
    const int bo = bucketOffs[b], eo = bucketOffs[b + 1];

    hist[tid] = 0;
    __syncthreads();
    for (int i = bo + tid; i < eo; i += 256)
        atomicAdd(&hist[packed[i] >> 24], 1);
    __syncthreads();

    int v = hist[tid];
    scan[tid] = v;
    __syncthreads();
    for (int off = 1; off < BK_NODES; off <<= 1) {
        int u = (tid >= off) ? scan[tid - off] : 0;
        __syncthreads();
        scan[tid] += u;
        __syncthreads();
    }
    const int excl = scan[tid] - v;

    const int node = b * BK_NODES + tid;
    if (node < N) {
        offs[node] = bo + excl;
        dinv[node] = rsqrtf((float)v + 1.0f);   // +1 self loop
        if (node == N - 1) offs[N] = eo;
    }

    hist[tid] = bo + excl;  // reuse as cursor
    __syncthreads();
    for (int i = bo + tid; i < eo; i += 256) {
        const uint_t pv = packed[i];
        const int p = atomicAdd(&hist[pv >> 24], 1);
        list[p] = (int)(pv & 0xFFFFFFu);
    }
}

// ---------------------------------------------------------------------------
// g(bf16) = (x @ W) * dinv[row].  512 thr: 64 slots x 8 cg; 4 rows/slot.
// Epilogue packs 8 f32 -> 8 bf16 (RNE) = one uint4 store per row.
// ---------------------------------------------------------------------------
__global__ __launch_bounds__(512) void k_gemm_scale(
    const float* __restrict__ x, const float* __restrict__ W,
    const float* __restrict__ dinv, ushort_t* __restrict__ g2, int N)
{
    __shared__ float Wlds[IN_CH * OUT_CH];  // 64 KB
    const int tid = threadIdx.x;
    for (int i = tid * 4; i < IN_CH * OUT_CH; i += 512 * 4) {
        *(float4*)&Wlds[i] = *(const float4*)&W[i];
    }
    __syncthreads();

    const int slot = tid >> 3;
    const int cg = (tid & 7) * 8;
    const int row0 = blockIdx.x * 256 + slot * 4;

    float a[4][8];
#pragma unroll
    for (int r = 0; r < 4; ++r)
#pragma unroll
        for (int c = 0; c < 8; ++c) a[r][c] = 0.f;

    const int rmax = (row0 + 4 <= N) ? 4 : max(0, N - row0);

    for (int k = 0; k < IN_CH; k += 4) {
        float4 xv[4];
#pragma unroll
        for (int r = 0; r < 4; ++r) {
            const int row = (r < rmax) ? (row0 + r) : (N - 1);
            xv[r] = *(const float4*)&x[(size_t)row * IN_CH + k];
        }
        const float xs[4][4] = {
            {xv[0].x, xv[0].y, xv[0].z, xv[0].w},
            {xv[1].x, xv[1].y, xv[1].z, xv[1].w},
            {xv[2].x, xv[2].y, xv[2].z, xv[2].w},
            {xv[3].x, xv[3].y, xv[3].z, xv[3].w}};
#pragma unroll
        for (int kk = 0; kk < 4; ++kk) {
            const float4 w0 = *(const float4*)&Wlds[(k + kk) * OUT_CH + cg];
            const float4 w1 = *(const float4*)&Wlds[(k + kk) * OUT_CH + cg + 4];
#pragma unroll
            for (int r = 0; r < 4; ++r) {
                a[r][0] += xs[r][kk] * w0.x; a[r][1] += xs[r][kk] * w0.y;
                a[r][2] += xs[r][kk] * w0.z; a[r][3] += xs[r][kk] * w0.w;
                a[r][4] += xs[r][kk] * w1.x; a[r][5] += xs[r][kk] * w1.y;
                a[r][6] += xs[r][kk] * w1.z; a[r][7] += xs[r][kk] * w1.w;
            }
        }
    }

#pragma unroll
    for (int r = 0; r < 4; ++r) {
        if (r < rmax) {
            const int row = row0 + r;
            const float dv = dinv[row];
            uint_t pk[4];
#pragma unroll
            for (int c = 0; c < 4; ++c)
                pk[c] = f2b(a[r][2 * c] * dv) | (f2b(a[r][2 * c + 1] * dv) << 16);
            *(uint4*)&g2[(size_t)row * OUT_CH + cg] =
                make_uint4(pk[0], pk[1], pk[2], pk[3]);
        }
    }
}

// ---------------------------------------------------------------------------
// One wave per node: bf16 gathers (128 B/row) over CSR list, fp32 accumulate,
// fused bias/log_softmax.
// ---------------------------------------------------------------------------
__global__ void k_aggregate(const int* __restrict__ offs, const int* __restrict__ list,
                            const ushort_t* __restrict__ g2, const float* __restrict__ b,
                            float* __restrict__ out, int N)
{
    const int lane = threadIdx.x & 63;
    int wid = (blockIdx.x * blockDim.x + threadIdx.x) >> 6;
    const int nw = (gridDim.x * blockDim.x) >> 6;
    const float bc = b[lane];

    for (int i = wid; i < N; i += nw) {
        const int start = offs[i];
        const int end = offs[i + 1];
        float acc = b2f(g2[(size_t)i * OUT_CH + lane]);  // self loop (g = h*dinv)

        for (int e0 = start; e0 < end; e0 += 64) {
            const int n = min(64, end - e0);
            const int idx = (lane < n) ? list[e0 + lane] : 0;
            for (int j = 0; j < n; ++j) {
                const int s = __shfl(idx, j);
                acc += b2f(g2[(size_t)s * OUT_CH + lane]);
            }
        }

        const float dinv = rsqrtf((float)(end - start + 1));
        const float z = acc * dinv + bc;

        float m = z;
#pragma unroll
        for (int off = 32; off; off >>= 1) m = fmaxf(m, __shfl_xor(m, off));
        float ev = __expf(z - m);
        float s = ev;
#pragma unroll
        for (int off = 32; off; off >>= 1) s += __shfl_xor(s, off);
        out[(size_t)i * OUT_CH + lane] = z - m - __logf(s);
    }
}

// ---------------------------------------------------------------------------
extern "C" void kernel_launch(void* const* d_in, const int* in_sizes, int n_in,
                              void* d_out, int out_size, void* d_ws, size_t ws_size,
                              hipStream_t stream) {
    const float* x  = (const float*)d_in[0];
    const int*   ei = (const int*)d_in[1];
    const float* W  = (const float*)d_in[2];
    const float* b  = (const float*)d_in[3];
    float* out = (float*)d_out;

    const int N = in_sizes[0] / IN_CH;  // 100000
    const int E = in_sizes[1] / 2;      // 1600000
    const int* src = ei;
    const int* dst = ei + E;

    const int nbk = (N + BK_NODES - 1) >> BK_LOG;          // 391
    const int ndist = (E + DIST_TILE - 1) / DIST_TILE;     // 98

    // ws: bucketCnt[1024] | bucketOffs[1025] | bucketCur[1024] |
    //     packed[E] | list[E] | offs[N+1] | dinv[N] | g2[N*64 bf16]  (~27 MB)
    char* p = (char*)d_ws;
    auto alloc = [&](size_t bytes) { char* q = p; p += (bytes + 255) & ~(size_t)255; return q; };
    int*      bucketCnt  = (int*)alloc(NBK_CAP * 4);
    int*      bucketOffs = (int*)alloc((NBK_CAP + 1) * 4);
    int*      bucketCur  = (int*)alloc(NBK_CAP * 4);
    uint_t*   packed     = (uint_t*)alloc((size_t)E * 4);
    int*      list       = (int*)alloc((size_t)E * 4);
    int*      offs       = (int*)alloc((size_t)(N + 1) * 4);
    float*    dinv       = (float*)alloc((size_t)N * 4);
    ushort_t* g2         = (ushort_t*)alloc((size_t)N * OUT_CH * 2);

    k_zero      <<<(nbk + 255) / 256, 256, 0, stream>>>(bucketCnt, nbk);
    k_bcount    <<<392, 256, 0, stream>>>(dst, bucketCnt, E, nbk);
    k_bscan     <<<1, NBK_CAP, 0, stream>>>(bucketCnt, bucketOffs, bucketCur, nbk);
    k_distribute<<<ndist, 256, 0, stream>>>(src, dst, bucketCur, packed, E, nbk);
    k_sortbucket<<<nbk, 256, 0, stream>>>(packed, bucketOffs, offs, list, dinv, N);
    k_gemm_scale<<<(N + 255) / 256, 512, 0, stream>>>(x, W, dinv, g2, N);
    k_aggregate <<<4096, 256, 0, stream>>>(offs, list, g2, b, out, N);
}

// Round 11
// 206.142 us; speedup vs baseline: 4.5163x; 1.2344x over previous
//
#include <hip/hip_runtime.h>
#include <math.h>

#define IN_CH 256
#define OUT_CH 64
#define BK_LOG 8
#define BK_NODES 256            // nodes per bucket
#define NBK_CAP 1024            // max buckets (N <= 262144)
#define DIST_TILE 16384         // edges per distribute block

typedef unsigned short ushort_t;
typedef unsigned int uint_t;

__device__ __forceinline__ float b2f(uint_t u) {  // low 16 bits = bf16
    union { uint_t i; float f; } c; c.i = u << 16; return c.f;
}
__device__ __forceinline__ uint_t f2b(float f) {  // round-to-nearest-even
    union { float f; uint_t i; } c; c.f = f;
    return (c.i + 0x7FFFu + ((c.i >> 16) & 1u)) >> 16;
}

// ---------------------------------------------------------------------------
__global__ void k_zero(int* __restrict__ p, int n) {
    int i = blockIdx.x * blockDim.x + threadIdx.x;
    if (i < n) p[i] = 0;
}

// ---------------------------------------------------------------------------
// Per-block LDS histogram of bucket ids; flush with one atomic per bucket.
// ---------------------------------------------------------------------------
__global__ void k_bcount(const int* __restrict__ dst, int* __restrict__ bucketCnt,
                         int E, int nbk) {
    __shared__ int hist[NBK_CAP];
    const int tid = threadIdx.x;
    for (int b = tid; b < nbk; b += blockDim.x) hist[b] = 0;
    __syncthreads();
    int i = blockIdx.x * blockDim.x + tid;
    const int stride = gridDim.x * blockDim.x;
    for (; i < E; i += stride) atomicAdd(&hist[dst[i] >> BK_LOG], 1);
    __syncthreads();
    for (int b = tid; b < nbk; b += blockDim.x)
        if (hist[b]) atomicAdd(&bucketCnt[b], hist[b]);
}

// ---------------------------------------------------------------------------
// Exclusive scan of bucketCnt -> bucketOffs[0..nbk]; bucketCur = offs.
// ---------------------------------------------------------------------------
__global__ void k_bscan(const int* __restrict__ bucketCnt, int* __restrict__ bucketOffs,
                        int* __restrict__ bucketCur, int nbk) {
    __shared__ int sdata[NBK_CAP];
    const int t = threadIdx.x;
    const int orig = (t < nbk) ? bucketCnt[t] : 0;
    sdata[t] = orig;
    __syncthreads();
    for (int off = 1; off < NBK_CAP; off <<= 1) {
        int v = (t >= off) ? sdata[t - off] : 0;
        __syncthreads();
        sdata[t] += v;
        __syncthreads();
    }
    if (t < nbk) {
        const int excl = sdata[t] - orig;
        bucketOffs[t] = excl;
        bucketCur[t] = excl;
        if (t == nbk - 1) bucketOffs[nbk] = sdata[t];
    }
}

// ---------------------------------------------------------------------------
// Bucket-sort edges into packed[] = src | (dst&255)<<24, contiguous per-block
// runs reserved with one global atomic per bucket per block.
// ---------------------------------------------------------------------------
__global__ __launch_bounds__(256) void k_distribute(
    const int* __restrict__ src, const int* __restrict__ dst,
    int* __restrict__ bucketCur, uint_t* __restrict__ packed,
    int E, int nbk)
{
    __shared__ int hist[NBK_CAP];
    __shared__ int base[NBK_CAP];
    const int tid = threadIdx.x;
    const int t0 = blockIdx.x * DIST_TILE;
    const int t1 = min(E, t0 + DIST_TILE);

    for (int b = tid; b < nbk; b += 256) hist[b] = 0;
    __syncthreads();
    for (int i = t0 + tid; i < t1; i += 256) atomicAdd(&hist[dst[i] >> BK_LOG], 1);
    __syncthreads();
    for (int b = tid; b < nbk; b += 256)
        base[b] = hist[b] ? atomicAdd(&bucketCur[b], hist[b]) : 0;
    __syncthreads();
    for (int i = t0 + tid; i < t1; i += 256) {
        const int d = dst[i];
        const int p = atomicAdd(&base[d >> BK_LOG], 1);
        packed[p] = (uint_t)src[i] | ((uint_t)(d & (BK_NODES - 1)) << 24);
    }
}

// ---------------------------------------------------------------------------
// One block per bucket: LDS histogram of local dst -> per-node offs + dinv,
// then LDS-cursor counting sort to exact dst order: list[p] = src.
// ---------------------------------------------------------------------------
__global__ __launch_bounds__(256) void k_sortbucket(
    const uint_t* __restrict__ packed, const int* __restrict__ bucketOffs,
    int* __restrict__ offs, int* __restrict__ list, float* __restrict__ dinv, int N)
{
    __shared__ int hist[BK_NODES];
    __shared__ int scan[BK_NODES];
    const int tid = threadIdx.x;
    const int b = blockIdx.x;
    const int bo = bucketOffs[b], eo = bucketOffs[b + 1];

    hist[tid] = 0;
    __syncthreads();
    for (int i = bo + tid; i < eo; i += 256)
        atomicAdd(&hist[packed[i] >> 24], 1);
    __syncthreads();

    int v = hist[tid];
    scan[tid] = v;
    __syncthreads();
    for (int off = 1; off < BK_NODES; off <<= 1) {
        int u = (tid >= off) ? scan[tid - off] : 0;
        __syncthreads();
        scan[tid] += u;
        __syncthreads();
    }
    const int excl = scan[tid] - v;

    const int node = b * BK_NODES + tid;
    if (node < N) {
        offs[node] = bo + excl;
        dinv[node] = rsqrtf((float)v + 1.0f);   // +1 self loop
        if (node == N - 1) offs[N] = eo;
    }

    hist[tid] = bo + excl;  // reuse as cursor
    __syncthreads();
    for (int i = bo + tid; i < eo; i += 256) {
        const uint_t pv = packed[i];
        const int p = atomicAdd(&hist[pv >> 24], 1);
        list[p] = (int)(pv & 0xFFFFFFu);
    }
}

// ---------------------------------------------------------------------------
// g(bf16) = (x @ W) * dinv[row].  512 thr: 64 slots x 8 cg; 4 rows/slot.
// ---------------------------------------------------------------------------
__global__ __launch_bounds__(512) void k_gemm_scale(
    const float* __restrict__ x, const float* __restrict__ W,
    const float* __restrict__ dinv, ushort_t* __restrict__ g2, int N)
{
    __shared__ float Wlds[IN_CH * OUT_CH];  // 64 KB
    const int tid = threadIdx.x;
    for (int i = tid * 4; i < IN_CH * OUT_CH; i += 512 * 4) {
        *(float4*)&Wlds[i] = *(const float4*)&W[i];
    }
    __syncthreads();

    const int slot = tid >> 3;
    const int cg = (tid & 7) * 8;
    const int row0 = blockIdx.x * 256 + slot * 4;

    float a[4][8];
#pragma unroll
    for (int r = 0; r < 4; ++r)
#pragma unroll
        for (int c = 0; c < 8; ++c) a[r][c] = 0.f;

    const int rmax = (row0 + 4 <= N) ? 4 : max(0, N - row0);

    for (int k = 0; k < IN_CH; k += 4) {
        float4 xv[4];
#pragma unroll
        for (int r = 0; r < 4; ++r) {
            const int row = (r < rmax) ? (row0 + r) : (N - 1);
            xv[r] = *(const float4*)&x[(size_t)row * IN_CH + k];
        }
        const float xs[4][4] = {
            {xv[0].x, xv[0].y, xv[0].z, xv[0].w},
            {xv[1].x, xv[1].y, xv[1].z, xv[1].w},
            {xv[2].x, xv[2].y, xv[2].z, xv[2].w},
            {xv[3].x, xv[3].y, xv[3].z, xv[3].w}};
#pragma unroll
        for (int kk = 0; kk < 4; ++kk) {
            const float4 w0 = *(const float4*)&Wlds[(k + kk) * OUT_CH + cg];
            const float4 w1 = *(const float4*)&Wlds[(k + kk) * OUT_CH + cg + 4];
#pragma unroll
            for (int r = 0; r < 4; ++r) {
                a[r][0] += xs[r][kk] * w0.x; a[r][1] += xs[r][kk] * w0.y;
                a[r][2] += xs[r][kk] * w0.z; a[r][3] += xs[r][kk] * w0.w;
                a[r][4] += xs[r][kk] * w1.x; a[r][5] += xs[r][kk] * w1.y;
                a[r][6] += xs[r][kk] * w1.z; a[r][7] += xs[r][kk] * w1.w;
            }
        }
    }

#pragma unroll
    for (int r = 0; r < 4; ++r) {
        if (r < rmax) {
            const int row = row0 + r;
            const float dv = dinv[row];
            uint_t pk[4];
#pragma unroll
            for (int c = 0; c < 4; ++c)
                pk[c] = f2b(a[r][2 * c] * dv) | (f2b(a[r][2 * c + 1] * dv) << 16);
            *(uint4*)&g2[(size_t)row * OUT_CH + cg] =
                make_uint4(pk[0], pk[1], pk[2], pk[3]);
        }
    }
}

// ---------------------------------------------------------------------------
// One wave per node, MLP-oriented: lanes 0-31 take even-position edges,
// lanes 32-63 odd ones. Each lane loads one uint (2 bf16 channels); one
// global_load_dword covers 2 edge rows. Unroll x4 -> 4 independent gathers
// in flight. Halves combine via shfl_xor(32); fused bias + log_softmax.
// ---------------------------------------------------------------------------
__global__ void k_aggregate(const int* __restrict__ offs, const int* __restrict__ list,
                            const ushort_t* __restrict__ g2, const float* __restrict__ b,
                            float* __restrict__ out, int N)
{
    const int lane = threadIdx.x & 63;
    const int c2 = lane & 31;         // uint index in row; channels 2*c2, 2*c2+1
    const int half = lane >> 5;       // 0 or 1
    int wid = (blockIdx.x * blockDim.x + threadIdx.x) >> 6;
    const int nw = (gridDim.x * blockDim.x) >> 6;
    const float bc0 = b[2 * c2], bc1 = b[2 * c2 + 1];

    for (int i = wid; i < N; i += nw) {
        const int start = offs[i];
        const int end = offs[i + 1];
        const int deg = end - start;
        float acc0 = 0.f, acc1 = 0.f;

        int e = start + half;  // this half's edge positions: e, e+2, e+4, ...
        for (; e + 6 < end; e += 8) {   // 4 edges per half, 8 per wave
            const int s0 = list[e];
            const int s1 = list[e + 2];
            const int s2 = list[e + 4];
            const int s3 = list[e + 6];
            const uint_t v0 = *(const uint_t*)&g2[(size_t)s0 * OUT_CH + c2 * 2];
            const uint_t v1 = *(const uint_t*)&g2[(size_t)s1 * OUT_CH + c2 * 2];
            const uint_t v2 = *(const uint_t*)&g2[(size_t)s2 * OUT_CH + c2 * 2];
            const uint_t v3 = *(const uint_t*)&g2[(size_t)s3 * OUT_CH + c2 * 2];
            acc0 += b2f(v0 & 0xFFFFu) + b2f(v1 & 0xFFFFu)
                  + b2f(v2 & 0xFFFFu) + b2f(v3 & 0xFFFFu);
            acc1 += b2f(v0 >> 16) + b2f(v1 >> 16)
                  + b2f(v2 >> 16) + b2f(v3 >> 16);
        }
        for (; e < end; e += 2) {
            const int s = list[e];
            const uint_t v = *(const uint_t*)&g2[(size_t)s * OUT_CH + c2 * 2];
            acc0 += b2f(v & 0xFFFFu);
            acc1 += b2f(v >> 16);
        }

        // combine the two halves
        acc0 += __shfl_xor(acc0, 32);
        acc1 += __shfl_xor(acc1, 32);

        // self loop
        const uint_t sv = *(const uint_t*)&g2[(size_t)i * OUT_CH + c2 * 2];
        acc0 += b2f(sv & 0xFFFFu);
        acc1 += b2f(sv >> 16);

        const float dinv = rsqrtf((float)deg + 1.0f);
        const float z0 = acc0 * dinv + bc0;
        const float z1 = acc1 * dinv + bc1;

        float m = fmaxf(z0, z1);
#pragma unroll
        for (int off = 16; off; off >>= 1) m = fmaxf(m, __shfl_xor(m, off));
        float s = __expf(z0 - m) + __expf(z1 - m);
#pragma unroll
        for (int off = 16; off; off >>= 1) s += __shfl_xor(s, off);
        const float ls = __logf(s);

        if (half == 0) {
            *(float2*)&out[(size_t)i * OUT_CH + 2 * c2] =
                make_float2(z0 - m - ls, z1 - m - ls);
        }
    }
}

// ---------------------------------------------------------------------------
extern "C" void kernel_launch(void* const* d_in, const int* in_sizes, int n_in,
                              void* d_out, int out_size, void* d_ws, size_t ws_size,
                              hipStream_t stream) {
    const float* x  = (const float*)d_in[0];
    const int*   ei = (const int*)d_in[1];
    const float* W  = (const float*)d_in[2];
    const float* b  = (const float*)d_in[3];
    float* out = (float*)d_out;

    const int N = in_sizes[0] / IN_CH;  // 100000
    const int E = in_sizes[1] / 2;      // 1600000
    const int* src = ei;
    const int* dst = ei + E;

    const int nbk = (N + BK_NODES - 1) >> BK_LOG;          // 391
    const int ndist = (E + DIST_TILE - 1) / DIST_TILE;     // 98

    // ws: bucketCnt[1024] | bucketOffs[1025] | bucketCur[1024] |
    //     packed[E] | list[E] | offs[N+1] | dinv[N] | g2[N*64 bf16]  (~27 MB)
    char* p = (char*)d_ws;
    auto alloc = [&](size_t bytes) { char* q = p; p += (bytes + 255) & ~(size_t)255; return q; };
    int*      bucketCnt  = (int*)alloc(NBK_CAP * 4);
    int*      bucketOffs = (int*)alloc((NBK_CAP + 1) * 4);
    int*      bucketCur  = (int*)alloc(NBK_CAP * 4);
    uint_t*   packed     = (uint_t*)alloc((size_t)E * 4);
    int*      list       = (int*)alloc((size_t)E * 4);
    int*      offs       = (int*)alloc((size_t)(N + 1) * 4);
    float*    dinv       = (float*)alloc((size_t)N * 4);
    ushort_t* g2         = (ushort_t*)alloc((size_t)N * OUT_CH * 2);

    k_zero      <<<(nbk + 255) / 256, 256, 0, stream>>>(bucketCnt, nbk);
    k_bcount    <<<392, 256, 0, stream>>>(dst, bucketCnt, E, nbk);
    k_bscan     <<<1, NBK_CAP, 0, stream>>>(bucketCnt, bucketOffs, bucketCur, nbk);
    k_distribute<<<ndist, 256, 0, stream>>>(src, dst, bucketCur, packed, E, nbk);
    k_sortbucket<<<nbk, 256, 0, stream>>>(packed, bucketOffs, offs, list, dinv, N);
    k_gemm_scale<<<(N + 255) / 256, 512, 0, stream>>>(x, W, dinv, g2, N);
    k_aggregate <<<4096, 256, 0, stream>>>(offs, list, g2, b, out, N);
}

// Round 12
// 172.704 us; speedup vs baseline: 5.3908x; 1.1936x over previous
//
#include <hip/hip_runtime.h>
#include <math.h>

#define IN_CH 256
#define OUT_CH 64
#define BK_LOG 8
#define BK_NODES 256            // nodes per bucket
#define NBK_CAP 1024            // max buckets (N <= 262144)
#define DIST_TILE 16384         // edges per distribute block

typedef unsigned short ushort_t;
typedef unsigned int uint_t;
typedef __attribute__((ext_vector_type(8))) short bf16x8;
typedef __attribute__((ext_vector_type(4))) float f32x4;

__device__ __forceinline__ float b2f(uint_t u) {  // low 16 bits = bf16
    union { uint_t i; float f; } c; c.i = u << 16; return c.f;
}
__device__ __forceinline__ uint_t f2b(float f) {  // round-to-nearest-even
    union { float f; uint_t i; } c; c.f = f;
    return (c.i + 0x7FFFu + ((c.i >> 16) & 1u)) >> 16;
}

// ---------------------------------------------------------------------------
__global__ void k_zero(int* __restrict__ p, int n) {
    int i = blockIdx.x * blockDim.x + threadIdx.x;
    if (i < n) p[i] = 0;
}

// ---------------------------------------------------------------------------
// Per-block LDS histogram of bucket ids; flush with one atomic per bucket.
// ---------------------------------------------------------------------------
__global__ void k_bcount(const int* __restrict__ dst, int* __restrict__ bucketCnt,
                         int E, int nbk) {
    __shared__ int hist[NBK_CAP];
    const int tid = threadIdx.x;
    for (int b = tid; b < nbk; b += blockDim.x) hist[b] = 0;
    __syncthreads();
    int i = blockIdx.x * blockDim.x + tid;
    const int stride = gridDim.x * blockDim.x;
    for (; i < E; i += stride) atomicAdd(&hist[dst[i] >> BK_LOG], 1);
    __syncthreads();
    for (int b = tid; b < nbk; b += blockDim.x)
        if (hist[b]) atomicAdd(&bucketCnt[b], hist[b]);
}

// ---------------------------------------------------------------------------
// Exclusive scan of bucketCnt -> bucketOffs[0..nbk]; bucketCur = offs.
// ---------------------------------------------------------------------------
__global__ void k_bscan(const int* __restrict__ bucketCnt, int* __restrict__ bucketOffs,
                        int* __restrict__ bucketCur, int nbk) {
    __shared__ int sdata[NBK_CAP];
    const int t = threadIdx.x;
    const int orig = (t < nbk) ? bucketCnt[t] : 0;
    sdata[t] = orig;
    __syncthreads();
    for (int off = 1; off < NBK_CAP; off <<= 1) {
        int v = (t >= off) ? sdata[t - off] : 0;
        __syncthreads();
        sdata[t] += v;
        __syncthreads();
    }
    if (t < nbk) {
        const int excl = sdata[t] - orig;
        bucketOffs[t] = excl;
        bucketCur[t] = excl;
        if (t == nbk - 1) bucketOffs[nbk] = sdata[t];
    }
}

// ---------------------------------------------------------------------------
// Bucket-sort edges into packed[] = src | (dst&255)<<24, contiguous per-block
// runs reserved with one global atomic per bucket per block.
// ---------------------------------------------------------------------------
__global__ __launch_bounds__(256) void k_distribute(
    const int* __restrict__ src, const int* __restrict__ dst,
    int* __restrict__ bucketCur, uint_t* __restrict__ packed,
    int E, int nbk)
{
    __shared__ int hist[NBK_CAP];
    __shared__ int base[NBK_CAP];
    const int tid = threadIdx.x;
    const int t0 = blockIdx.x * DIST_TILE;
    const int t1 = min(E, t0 + DIST_TILE);

    for (int b = tid; b < nbk; b += 256) hist[b] = 0;
    __syncthreads();
    for (int i = t0 + tid; i < t1; i += 256) atomicAdd(&hist[dst[i] >> BK_LOG], 1);
    __syncthreads();
    for (int b = tid; b < nbk; b += 256)
        base[b] = hist[b] ? atomicAdd(&bucketCur[b], hist[b]) : 0;
    __syncthreads();
    for (int i = t0 + tid; i < t1; i += 256) {
        const int d = dst[i];
        const int p = atomicAdd(&base[d >> BK_LOG], 1);
        packed[p] = (uint_t)src[i] | ((uint_t)(d & (BK_NODES - 1)) << 24);
    }
}

// ---------------------------------------------------------------------------
// One block per bucket: LDS histogram of local dst -> per-node offs + dinv,
// then LDS-cursor counting sort to exact dst order: list[p] = src.
// ---------------------------------------------------------------------------
__global__ __launch_bounds__(256) void k_sortbucket(
    const uint_t* __restrict__ packed, const int* __restrict__ bucketOffs,
    int* __restrict__ offs, int* __restrict__ list, float* __restrict__ dinv, int N)
{
    __shared__ int hist[BK_NODES];
    __shared__ int scan[BK_NODES];
    const int tid = threadIdx.x;
    const int b = blockIdx.x;
    const int bo = bucketOffs[b], eo = bucketOffs[b + 1];

    hist[tid] = 0;
    __syncthreads();
    for (int i = bo + tid; i < eo; i += 256)
        atomicAdd(&hist[packed[i] >> 24], 1);
    __syncthreads();

    int v = hist[tid];
    scan[tid] = v;
    __syncthreads();
    for (int off = 1; off < BK_NODES; off <<= 1) {
        int u = (tid >= off) ? scan[tid - off] : 0;
        __syncthreads();
        scan[tid] += u;
        __syncthreads();
    }
    const int excl = scan[tid] - v;

    const int node = b * BK_NODES + tid;
    if (node < N) {
        offs[node] = bo + excl;
        dinv[node] = rsqrtf((float)v + 1.0f);   // +1 self loop
        if (node == N - 1) offs[N] = eo;
    }

    hist[tid] = bo + excl;  // reuse as cursor
    __syncthreads();
    for (int i = bo + tid; i < eo; i += 256) {
        const uint_t pv = packed[i];
        const int p = atomicAdd(&hist[pv >> 24], 1);
        list[p] = (int)(pv & 0xFFFFFFu);
    }
}

// ---------------------------------------------------------------------------
// Wt[col][k] = bf16(W[k][col])  (64 x 256, 32 KB). Coalesced ushort writes.
// ---------------------------------------------------------------------------
__global__ __launch_bounds__(256) void k_prepW(const float* __restrict__ W,
                                               ushort_t* __restrict__ Wt) {
    const int j = blockIdx.x * 256 + threadIdx.x;   // 0..16383
    const int col = j >> 8, k = j & 255;
    Wt[j] = (ushort_t)f2b(W[k * OUT_CH + col]);
}

// ---------------------------------------------------------------------------
// g2(bf16) = (x @ W) * dinv[row] via MFMA 16x16x32 bf16.
// 256 thr = 4 waves x 16 rows = 64 rows/block. Wt staged in 32 KB LDS with
// XOR swizzle (byte ^= (col&7)<<4) to kill the stride-512B bank conflict.
// A-frag: lane holds x[rowbase+(l&15)][k0+(l>>4)*8 .. +8) (coalesced f32,
// converted to bf16 in-register). B-frag: Wt[c*16+(l&15)][same k range].
// D layout: row = (l>>4)*4 + reg, col = c*16 + (l&15)   [m89-verified].
// ---------------------------------------------------------------------------
__global__ __launch_bounds__(256) void k_gemm_mfma(
    const float* __restrict__ x, const ushort_t* __restrict__ Wt,
    const float* __restrict__ dinv, ushort_t* __restrict__ g2, int N)
{
    __shared__ ushort_t Ws[OUT_CH * IN_CH];  // 32 KB, XOR-swizzled
    const int tid = threadIdx.x;
    for (int i = tid * 8; i < OUT_CH * IN_CH; i += 256 * 8) {
        const int col = i >> 8;
        const uint_t byte = (uint_t)(i * 2) ^ ((uint_t)(col & 7) << 4);
        *(uint4*)((char*)Ws + byte) = *(const uint4*)&Wt[i];
    }
    __syncthreads();

    const int lane = tid & 63;
    const int l16 = lane & 15;
    const int lq = lane >> 4;
    const int rowbase = blockIdx.x * 64 + (tid >> 6) * 16;

    const int arow = min(rowbase + l16, N - 1);
    const float* __restrict__ xr = x + (size_t)arow * IN_CH + lq * 8;

    f32x4 acc[4];
#pragma unroll
    for (int c = 0; c < 4; ++c) acc[c] = (f32x4){0.f, 0.f, 0.f, 0.f};

    for (int k0 = 0; k0 < IN_CH; k0 += 32) {
        const float4 xa = *(const float4*)&xr[k0];
        const float4 xb = *(const float4*)&xr[k0 + 4];
        bf16x8 a;
        a[0] = (short)f2b(xa.x); a[1] = (short)f2b(xa.y);
        a[2] = (short)f2b(xa.z); a[3] = (short)f2b(xa.w);
        a[4] = (short)f2b(xb.x); a[5] = (short)f2b(xb.y);
        a[6] = (short)f2b(xb.z); a[7] = (short)f2b(xb.w);
        const int kk = (k0 + lq * 8) * 2;  // byte offset of k within a row
#pragma unroll
        for (int c = 0; c < 4; ++c) {
            const int col = c * 16 + l16;
            const uint_t byte = (uint_t)(col * 512 + kk) ^ ((uint_t)(col & 7) << 4);
            const bf16x8 bfrag = *(const bf16x8*)((const char*)Ws + byte);
            acc[c] = __builtin_amdgcn_mfma_f32_16x16x32_bf16(a, bfrag, acc[c], 0, 0, 0);
        }
    }

#pragma unroll
    for (int r = 0; r < 4; ++r) {
        const int row = rowbase + lq * 4 + r;
        if (row < N) {
            const float dv = dinv[row];
            const size_t o = (size_t)row * OUT_CH;
            g2[o +  0 + l16] = (ushort_t)f2b(acc[0][r] * dv);
            g2[o + 16 + l16] = (ushort_t)f2b(acc[1][r] * dv);
            g2[o + 32 + l16] = (ushort_t)f2b(acc[2][r] * dv);
            g2[o + 48 + l16] = (ushort_t)f2b(acc[3][r] * dv);
        }
    }
}

// ---------------------------------------------------------------------------
// One wave per node, MLP-oriented: lanes 0-31 take even-position edges,
// lanes 32-63 odd ones; each lane loads one uint (2 bf16 channels); unroll x4
// -> 4 independent gathers in flight per half. Fused bias + log_softmax.
// ---------------------------------------------------------------------------
__global__ void k_aggregate(const int* __restrict__ offs, const int* __restrict__ list,
                            const ushort_t* __restrict__ g2, const float* __restrict__ b,
                            float* __restrict__ out, int N)
{
    const int lane = threadIdx.x & 63;
    const int c2 = lane & 31;         // uint index in row; channels 2*c2, 2*c2+1
    const int half = lane >> 5;       // 0 or 1
    int wid = (blockIdx.x * blockDim.x + threadIdx.x) >> 6;
    const int nw = (gridDim.x * blockDim.x) >> 6;
    const float bc0 = b[2 * c2], bc1 = b[2 * c2 + 1];

    for (int i = wid; i < N; i += nw) {
        const int start = offs[i];
        const int end = offs[i + 1];
        const int deg = end - start;
        float acc0 = 0.f, acc1 = 0.f;

        int e = start + half;  // this half's edge positions: e, e+2, e+4, ...
        for (; e + 6 < end; e += 8) {   // 4 edges per half, 8 per wave
            const int s0 = list[e];
            const int s1 = list[e + 2];
            const int s2 = list[e + 4];
            const int s3 = list[e + 6];
            const uint_t v0 = *(const uint_t*)&g2[(size_t)s0 * OUT_CH + c2 * 2];
            const uint_t v1 = *(const uint_t*)&g2[(size_t)s1 * OUT_CH + c2 * 2];
            const uint_t v2 = *(const uint_t*)&g2[(size_t)s2 * OUT_CH + c2 * 2];
            const uint_t v3 = *(const uint_t*)&g2[(size_t)s3 * OUT_CH + c2 * 2];
            acc0 += b2f(v0 & 0xFFFFu) + b2f(v1 & 0xFFFFu)
                  + b2f(v2 & 0xFFFFu) + b2f(v3 & 0xFFFFu);
            acc1 += b2f(v0 >> 16) + b2f(v1 >> 16)
                  + b2f(v2 >> 16) + b2f(v3 >> 16);
        }
        for (; e < end; e += 2) {
            const int s = list[e];
            const uint_t v = *(const uint_t*)&g2[(size_t)s * OUT_CH + c2 * 2];
            acc0 += b2f(v & 0xFFFFu);
            acc1 += b2f(v >> 16);
        }

        acc0 += __shfl_xor(acc0, 32);
        acc1 += __shfl_xor(acc1, 32);

        const uint_t sv = *(const uint_t*)&g2[(size_t)i * OUT_CH + c2 * 2];
        acc0 += b2f(sv & 0xFFFFu);
        acc1 += b2f(sv >> 16);

        const float dinv = rsqrtf((float)deg + 1.0f);
        const float z0 = acc0 * dinv + bc0;
        const float z1 = acc1 * dinv + bc1;

        float m = fmaxf(z0, z1);
#pragma unroll
        for (int off = 16; off; off >>= 1) m = fmaxf(m, __shfl_xor(m, off));
        float s = __expf(z0 - m) + __expf(z1 - m);
#pragma unroll
        for (int off = 16; off; off >>= 1) s += __shfl_xor(s, off);
        const float ls = __logf(s);

        if (half == 0) {
            *(float2*)&out[(size_t)i * OUT_CH + 2 * c2] =
                make_float2(z0 - m - ls, z1 - m - ls);
        }
    }
}

// ---------------------------------------------------------------------------
extern "C" void kernel_launch(void* const* d_in, const int* in_sizes, int n_in,
                              void* d_out, int out_size, void* d_ws, size_t ws_size,
                              hipStream_t stream) {
    const float* x  = (const float*)d_in[0];
    const int*   ei = (const int*)d_in[1];
    const float* W  = (const float*)d_in[2];
    const float* b  = (const float*)d_in[3];
    float* out = (float*)d_out;

    const int N = in_sizes[0] / IN_CH;  // 100000
    const int E = in_sizes[1] / 2;      // 1600000
    const int* src = ei;
    const int* dst = ei + E;

    const int nbk = (N + BK_NODES - 1) >> BK_LOG;          // 391
    const int ndist = (E + DIST_TILE - 1) / DIST_TILE;     // 98

    // ws: bucketCnt[1024] | bucketOffs[1025] | bucketCur[1024] | Wt[16384 bf16]
    //     | packed[E] | list[E] | offs[N+1] | dinv[N] | g2[N*64 bf16]  (~27 MB)
    char* p = (char*)d_ws;
    auto alloc = [&](size_t bytes) { char* q = p; p += (bytes + 255) & ~(size_t)255; return q; };
    int*      bucketCnt  = (int*)alloc(NBK_CAP * 4);
    int*      bucketOffs = (int*)alloc((NBK_CAP + 1) * 4);
    int*      bucketCur  = (int*)alloc(NBK_CAP * 4);
    ushort_t* Wt         = (ushort_t*)alloc((size_t)OUT_CH * IN_CH * 2);
    uint_t*   packed     = (uint_t*)alloc((size_t)E * 4);
    int*      list       = (int*)alloc((size_t)E * 4);
    int*      offs       = (int*)alloc((size_t)(N + 1) * 4);
    float*    dinv       = (float*)alloc((size_t)N * 4);
    ushort_t* g2         = (ushort_t*)alloc((size_t)N * OUT_CH * 2);

    k_zero      <<<(nbk + 255) / 256, 256, 0, stream>>>(bucketCnt, nbk);
    k_prepW     <<<(OUT_CH * IN_CH) / 256, 256, 0, stream>>>(W, Wt);
    k_bcount    <<<392, 256, 0, stream>>>(dst, bucketCnt, E, nbk);
    k_bscan     <<<1, NBK_CAP, 0, stream>>>(bucketCnt, bucketOffs, bucketCur, nbk);
    k_distribute<<<ndist, 256, 0, stream>>>(src, dst, bucketCur, packed, E, nbk);
    k_sortbucket<<<nbk, 256, 0, stream>>>(packed, bucketOffs, offs, list, dinv, N);
    k_gemm_mfma <<<(N + 63) / 64, 256, 0, stream>>>(x, Wt, dinv, g2, N);
    k_aggregate <<<4096, 256, 0, stream>>>(offs, list, g2, b, out, N);
}

// Round 13
// 151.488 us; speedup vs baseline: 6.1457x; 1.1400x over previous
//
#include <hip/hip_runtime.h>
#include <math.h>

#define IN_CH 256
#define OUT_CH 64
#define BK_LOG 8
#define BK_NODES 256            // nodes per bucket
#define NBK_CAP 1024            // max buckets (N <= 262144)
#define DIST_TILE 2048          // edges per distribute block (782 blocks @ E=1.6M)

typedef unsigned short ushort_t;
typedef unsigned int uint_t;
typedef __attribute__((ext_vector_type(8))) short bf16x8;
typedef __attribute__((ext_vector_type(4))) float f32x4;

__device__ __forceinline__ float b2f(uint_t u) {  // low 16 bits = bf16
    union { uint_t i; float f; } c; c.i = u << 16; return c.f;
}
__device__ __forceinline__ uint_t f2b(float f) {  // round-to-nearest-even
    union { float f; uint_t i; } c; c.f = f;
    return (c.i + 0x7FFFu + ((c.i >> 16) & 1u)) >> 16;
}

// ---------------------------------------------------------------------------
__global__ void k_zero(int* __restrict__ p, int n) {
    int i = blockIdx.x * blockDim.x + threadIdx.x;
    if (i < n) p[i] = 0;
}

// ---------------------------------------------------------------------------
// Per-block LDS histogram of bucket ids; flush with one atomic per bucket.
// ---------------------------------------------------------------------------
__global__ void k_bcount(const int* __restrict__ dst, int* __restrict__ bucketCnt,
                         int E, int nbk) {
    __shared__ int hist[NBK_CAP];
    const int tid = threadIdx.x;
    for (int b = tid; b < nbk; b += blockDim.x) hist[b] = 0;
    __syncthreads();
    int i = blockIdx.x * blockDim.x + tid;
    const int stride = gridDim.x * blockDim.x;
    for (; i < E; i += stride) atomicAdd(&hist[dst[i] >> BK_LOG], 1);
    __syncthreads();
    for (int b = tid; b < nbk; b += blockDim.x)
        if (hist[b]) atomicAdd(&bucketCnt[b], hist[b]);
}

// ---------------------------------------------------------------------------
// Exclusive scan of bucketCnt -> bucketOffs[0..nbk]; bucketCur = offs.
// ---------------------------------------------------------------------------
__global__ void k_bscan(const int* __restrict__ bucketCnt, int* __restrict__ bucketOffs,
                        int* __restrict__ bucketCur, int nbk) {
    __shared__ int sdata[NBK_CAP];
    const int t = threadIdx.x;
    const int orig = (t < nbk) ? bucketCnt[t] : 0;
    sdata[t] = orig;
    __syncthreads();
    for (int off = 1; off < NBK_CAP; off <<= 1) {
        int v = (t >= off) ? sdata[t - off] : 0;
        __syncthreads();
        sdata[t] += v;
        __syncthreads();
    }
    if (t < nbk) {
        const int excl = sdata[t] - orig;
        bucketOffs[t] = excl;
        bucketCur[t] = excl;
        if (t == nbk - 1) bucketOffs[nbk] = sdata[t];
    }
}

// ---------------------------------------------------------------------------
// Bucket-sort edges into packed[] = src | (dst&255)<<24, contiguous per-block
// runs reserved with one global atomic per bucket per block.
// DIST_TILE=2048 -> 782 blocks (~3/CU) so latency is TLP-hidden.
// ---------------------------------------------------------------------------
__global__ __launch_bounds__(256) void k_distribute(
    const int* __restrict__ src, const int* __restrict__ dst,
    int* __restrict__ bucketCur, uint_t* __restrict__ packed,
    int E, int nbk)
{
    __shared__ int hist[NBK_CAP];
    __shared__ int base[NBK_CAP];
    const int tid = threadIdx.x;
    const int t0 = blockIdx.x * DIST_TILE;
    const int t1 = min(E, t0 + DIST_TILE);

    for (int b = tid; b < nbk; b += 256) hist[b] = 0;
    __syncthreads();
    for (int i = t0 + tid; i < t1; i += 256) atomicAdd(&hist[dst[i] >> BK_LOG], 1);
    __syncthreads();
    for (int b = tid; b < nbk; b += 256)
        base[b] = hist[b] ? atomicAdd(&bucketCur[b], hist[b]) : 0;
    __syncthreads();
    for (int i = t0 + tid; i < t1; i += 256) {
        const int d = dst[i];
        const int p = atomicAdd(&base[d >> BK_LOG], 1);
        packed[p] = (uint_t)src[i] | ((uint_t)(d & (BK_NODES - 1)) << 24);
    }
}

// ---------------------------------------------------------------------------
// One block per bucket: LDS histogram of local dst -> per-node offs + dinv,
// then LDS-cursor counting sort to exact dst order: list[p] = src.
// ---------------------------------------------------------------------------
__global__ __launch_bounds__(256) void k_sortbucket(
    const uint_t* __restrict__ packed, const int* __restrict__ bucketOffs,
    int* __restrict__ offs, int* __restrict__ list, float* __restrict__ dinv, int N)
{
    __shared__ int hist[BK_NODES];
    __shared__ int scan[BK_NODES];
    const int tid = threadIdx.x;
    const int b = blockIdx.x;
    const int bo = bucketOffs[b], eo = bucketOffs[b + 1];

    hist[tid] = 0;
    __syncthreads();
    for (int i = bo + tid; i < eo; i += 256)
        atomicAdd(&hist[packed[i] >> 24], 1);
    __syncthreads();

    int v = hist[tid];
    scan[tid] = v;
    __syncthreads();
    for (int off = 1; off < BK_NODES; off <<= 1) {
        int u = (tid >= off) ? scan[tid - off] : 0;
        __syncthreads();
        scan[tid] += u;
        __syncthreads();
    }
    const int excl = scan[tid] - v;

    const int node = b * BK_NODES + tid;
    if (node < N) {
        offs[node] = bo + excl;
        dinv[node] = rsqrtf((float)v + 1.0f);   // +1 self loop
        if (node == N - 1) offs[N] = eo;
    }

    hist[tid] = bo + excl;  // reuse as cursor
    __syncthreads();
    for (int i = bo + tid; i < eo; i += 256) {
        const uint_t pv = packed[i];
        const int p = atomicAdd(&hist[pv >> 24], 1);
        list[p] = (int)(pv & 0xFFFFFFu);
    }
}

// ---------------------------------------------------------------------------
// Wt[col][k] = bf16(W[k][col])  (64 x 256, 32 KB). Coalesced ushort writes.
// ---------------------------------------------------------------------------
__global__ __launch_bounds__(256) void k_prepW(const float* __restrict__ W,
                                               ushort_t* __restrict__ Wt) {
    const int j = blockIdx.x * 256 + threadIdx.x;   // 0..16383
    const int col = j >> 8, k = j & 255;
    Wt[j] = (ushort_t)f2b(W[k * OUT_CH + col]);
}

// ---------------------------------------------------------------------------
// g2(bf16) = (x @ W) * dinv[row] via MFMA 16x16x32 bf16.
// 256 thr = 4 waves x 16 rows = 64 rows/block. Wt staged in 32 KB LDS with
// XOR swizzle (byte ^= (col&7)<<4). D layout: row=(l>>4)*4+reg, col=l&15.
// ---------------------------------------------------------------------------
__global__ __launch_bounds__(256) void k_gemm_mfma(
    const float* __restrict__ x, const ushort_t* __restrict__ Wt,
    const float* __restrict__ dinv, ushort_t* __restrict__ g2, int N)
{
    __shared__ ushort_t Ws[OUT_CH * IN_CH];  // 32 KB, XOR-swizzled
    const int tid = threadIdx.x;
    for (int i = tid * 8; i < OUT_CH * IN_CH; i += 256 * 8) {
        const int col = i >> 8;
        const uint_t byte = (uint_t)(i * 2) ^ ((uint_t)(col & 7) << 4);
        *(uint4*)((char*)Ws + byte) = *(const uint4*)&Wt[i];
    }
    __syncthreads();

    const int lane = tid & 63;
    const int l16 = lane & 15;
    const int lq = lane >> 4;
    const int rowbase = blockIdx.x * 64 + (tid >> 6) * 16;

    const int arow = min(rowbase + l16, N - 1);
    const float* __restrict__ xr = x + (size_t)arow * IN_CH + lq * 8;

    f32x4 acc[4];
#pragma unroll
    for (int c = 0; c < 4; ++c) acc[c] = (f32x4){0.f, 0.f, 0.f, 0.f};

    for (int k0 = 0; k0 < IN_CH; k0 += 32) {
        const float4 xa = *(const float4*)&xr[k0];
        const float4 xb = *(const float4*)&xr[k0 + 4];
        bf16x8 a;
        a[0] = (short)f2b(xa.x); a[1] = (short)f2b(xa.y);
        a[2] = (short)f2b(xa.z); a[3] = (short)f2b(xa.w);
        a[4] = (short)f2b(xb.x); a[5] = (short)f2b(xb.y);
        a[6] = (short)f2b(xb.z); a[7] = (short)f2b(xb.w);
        const int kk = (k0 + lq * 8) * 2;  // byte offset of k within a row
#pragma unroll
        for (int c = 0; c < 4; ++c) {
            const int col = c * 16 + l16;
            const uint_t byte = (uint_t)(col * 512 + kk) ^ ((uint_t)(col & 7) << 4);
            const bf16x8 bfrag = *(const bf16x8*)((const char*)Ws + byte);
            acc[c] = __builtin_amdgcn_mfma_f32_16x16x32_bf16(a, bfrag, acc[c], 0, 0, 0);
        }
    }

#pragma unroll
    for (int r = 0; r < 4; ++r) {
        const int row = rowbase + lq * 4 + r;
        if (row < N) {
            const float dv = dinv[row];
            const size_t o = (size_t)row * OUT_CH;
            g2[o +  0 + l16] = (ushort_t)f2b(acc[0][r] * dv);
            g2[o + 16 + l16] = (ushort_t)f2b(acc[1][r] * dv);
            g2[o + 32 + l16] = (ushort_t)f2b(acc[2][r] * dv);
            g2[o + 48 + l16] = (ushort_t)f2b(acc[3][r] * dv);
        }
    }
}

// ---------------------------------------------------------------------------
// One wave per node, MLP-oriented: lanes 0-31 take even-position edges,
// lanes 32-63 odd ones; each lane loads one uint (2 bf16 channels); unroll x4
// -> 4 independent gathers in flight per half. Fused bias + log_softmax.
// ---------------------------------------------------------------------------
__global__ void k_aggregate(const int* __restrict__ offs, const int* __restrict__ list,
                            const ushort_t* __restrict__ g2, const float* __restrict__ b,
                            float* __restrict__ out, int N)
{
    const int lane = threadIdx.x & 63;
    const int c2 = lane & 31;         // uint index in row; channels 2*c2, 2*c2+1
    const int half = lane >> 5;       // 0 or 1
    int wid = (blockIdx.x * blockDim.x + threadIdx.x) >> 6;
    const int nw = (gridDim.x * blockDim.x) >> 6;
    const float bc0 = b[2 * c2], bc1 = b[2 * c2 + 1];

    for (int i = wid; i < N; i += nw) {
        const int start = offs[i];
        const int end = offs[i + 1];
        const int deg = end - start;
        float acc0 = 0.f, acc1 = 0.f;

        int e = start + half;  // this half's edge positions: e, e+2, e+4, ...
        for (; e + 6 < end; e += 8) {   // 4 edges per half, 8 per wave
            const int s0 = list[e];
            const int s1 = list[e + 2];
            const int s2 = list[e + 4];
            const int s3 = list[e + 6];
            const uint_t v0 = *(const uint_t*)&g2[(size_t)s0 * OUT_CH + c2 * 2];
            const uint_t v1 = *(const uint_t*)&g2[(size_t)s1 * OUT_CH + c2 * 2];
            const uint_t v2 = *(const uint_t*)&g2[(size_t)s2 * OUT_CH + c2 * 2];
            const uint_t v3 = *(const uint_t*)&g2[(size_t)s3 * OUT_CH + c2 * 2];
            acc0 += b2f(v0 & 0xFFFFu) + b2f(v1 & 0xFFFFu)
                  + b2f(v2 & 0xFFFFu) + b2f(v3 & 0xFFFFu);
            acc1 += b2f(v0 >> 16) + b2f(v1 >> 16)
                  + b2f(v2 >> 16) + b2f(v3 >> 16);
        }
        for (; e < end; e += 2) {
            const int s = list[e];
            const uint_t v = *(const uint_t*)&g2[(size_t)s * OUT_CH + c2 * 2];
            acc0 += b2f(v & 0xFFFFu);
            acc1 += b2f(v >> 16);
        }

        acc0 += __shfl_xor(acc0, 32);
        acc1 += __shfl_xor(acc1, 32);

        const uint_t sv = *(const uint_t*)&g2[(size_t)i * OUT_CH + c2 * 2];
        acc0 += b2f(sv & 0xFFFFu);
        acc1 += b2f(sv >> 16);

        const float dinv = rsqrtf((float)deg + 1.0f);
        const float z0 = acc0 * dinv + bc0;
        const float z1 = acc1 * dinv + bc1;

        float m = fmaxf(z0, z1);
#pragma unroll
        for (int off = 16; off; off >>= 1) m = fmaxf(m, __shfl_xor(m, off));
        float s = __expf(z0 - m) + __expf(z1 - m);
#pragma unroll
        for (int off = 16; off; off >>= 1) s += __shfl_xor(s, off);
        const float ls = __logf(s);

        if (half == 0) {
            *(float2*)&out[(size_t)i * OUT_CH + 2 * c2] =
                make_float2(z0 - m - ls, z1 - m - ls);
        }
    }
}

// ---------------------------------------------------------------------------
extern "C" void kernel_launch(void* const* d_in, const int* in_sizes, int n_in,
                              void* d_out, int out_size, void* d_ws, size_t ws_size,
                              hipStream_t stream) {
    const float* x  = (const float*)d_in[0];
    const int*   ei = (const int*)d_in[1];
    const float* W  = (const float*)d_in[2];
    const float* b  = (const float*)d_in[3];
    float* out = (float*)d_out;

    const int N = in_sizes[0] / IN_CH;  // 100000
    const int E = in_sizes[1] / 2;      // 1600000
    const int* src = ei;
    const int* dst = ei + E;

    const int nbk = (N + BK_NODES - 1) >> BK_LOG;          // 391
    const int ndist = (E + DIST_TILE - 1) / DIST_TILE;     // 782

    // ws: bucketCnt[1024] | bucketOffs[1025] | bucketCur[1024] | Wt[16384 bf16]
    //     | packed[E] | list[E] | offs[N+1] | dinv[N] | g2[N*64 bf16]  (~27 MB)
    char* p = (char*)d_ws;
    auto alloc = [&](size_t bytes) { char* q = p; p += (bytes + 255) & ~(size_t)255; return q; };
    int*      bucketCnt  = (int*)alloc(NBK_CAP * 4);
    int*      bucketOffs = (int*)alloc((NBK_CAP + 1) * 4);
    int*      bucketCur  = (int*)alloc(NBK_CAP * 4);
    ushort_t* Wt         = (ushort_t*)alloc((size_t)OUT_CH * IN_CH * 2);
    uint_t*   packed     = (uint_t*)alloc((size_t)E * 4);
    int*      list       = (int*)alloc((size_t)E * 4);
    int*      offs       = (int*)alloc((size_t)(N + 1) * 4);
    float*    dinv       = (float*)alloc((size_t)N * 4);
    ushort_t* g2         = (ushort_t*)alloc((size_t)N * OUT_CH * 2);

    k_zero      <<<(nbk + 255) / 256, 256, 0, stream>>>(bucketCnt, nbk);
    k_prepW     <<<(OUT_CH * IN_CH) / 256, 256, 0, stream>>>(W, Wt);
    k_bcount    <<<392, 256, 0, stream>>>(dst, bucketCnt, E, nbk);
    k_bscan     <<<1, NBK_CAP, 0, stream>>>(bucketCnt, bucketOffs, bucketCur, nbk);
    k_distribute<<<ndist, 256, 0, stream>>>(src, dst, bucketCur, packed, E, nbk);
    k_sortbucket<<<nbk, 256, 0, stream>>>(packed, bucketOffs, offs, list, dinv, N);
    k_gemm_mfma <<<(N + 63) / 64, 256, 0, stream>>>(x, Wt, dinv, g2, N);
    k_aggregate <<<4096, 256, 0, stream>>>(offs, list, g2, b, out, N);
}